// Round 4
// baseline (399.709 us; speedup 1.0000x reference)
//
#include <hip/hip_runtime.h>
#include <stdint.h>

typedef _Float16 f16;
typedef __attribute__((ext_vector_type(8))) _Float16 f16x8;
typedef __attribute__((ext_vector_type(4))) _Float16 f16x4;
typedef __attribute__((ext_vector_type(4))) float f32x4;

#define BM 128
#define BN 128
#define BK 32

typedef __attribute__((address_space(3))) uint32_t lds_u32;
typedef const __attribute__((address_space(1))) uint32_t glb_u32;

__device__ __forceinline__ void gload_lds16(const void* g, void* l) {
    // async global->LDS, 16B per lane; LDS dest = wave-uniform base + lane*16
    __builtin_amdgcn_global_load_lds((glb_u32*)g, (lds_u32*)l, 16, 0, 0);
}

// C[M,N] = A[M,K] * B[N,K]^T  (both f16 row-major), fp32 accumulate.
// LDS tile layout (conflict-free, verified R3: SQ_LDS_BANK_CONFLICT=0):
// per 16-row group g one 1024-B block; DMA lands lane ell at base+ell*16,
// lane ell fetches row (ell&15), k-chunk (ell>>4). Fragment read for the
// 16x16x32 MFMA is then exactly LDS[g*512 + lane*8 f16] -> one sequential
// 1024-B sweep per wave, zero bank conflicts; global side still 16x64B
// segments (coalescing kept).
// BK=32 keeps LDS at 16 KB: QKV grid needs 6 blocks/CU co-resident
// (1536/256); 32 KB capped residency at 5 -> tail round (R3 regression).
// OUT_MODE: 0 = fp32 flat [M,N] + bias
//           1 = f16 out, per-batch stride sCb, row-major [M,N] + bias
//           3 = fused QKV: gn<1024 -> Q flat f16 [M,1024]; <2048 -> K flat;
//               else V^T f16 [B][1024][2048] (batch from gm>>11)
// CAUSAL: 0 = none; 1 = triangular flat blockIdx.x; 2 = PV (Kend=m0+BM,
//         diagonal-paired m-tiles: y and M/BM-1-y)
template<int OUT_MODE, int CAUSAL>
__global__ __launch_bounds__(256, 2)
void gemm_bt(const f16* __restrict__ A, const f16* __restrict__ B,
             const float* __restrict__ bias, const float* __restrict__ bias2,
             const float* __restrict__ bias3,
             void* __restrict__ Cv, void* __restrict__ C2, void* __restrict__ C3,
             int M, int N, int K,
             long long sAb, long long sBb, long long sCb, float scale)
{
    int mtile, n0;
    if (CAUSAL == 1) {
        int rem = (int)blockIdx.x, mi = 0;
        while (rem > mi) { rem -= mi + 1; ++mi; }   // row mi has mi+1 n-blocks
        mtile = mi;
        n0 = rem * BN;
    } else {
        mtile = blockIdx.y;
        n0 = blockIdx.x * BN;
    }

    const int tid  = threadIdx.x;
    const int wave = tid >> 6;
    const int lane = tid & 63;
    const long long bz = blockIdx.z;
    A += bz * sAb;
    B += bz * sBb;

    __shared__ f16 As[BM * BK];  // 8 KB: 8 groups x 512 f16 (1024 B each)
    __shared__ f16 Bs[BM * BK];

    const int srowA = lane & 15;        // staging: row within 16-row group
    const int kq    = (lane >> 4) * 8;  // staging: k-chunk (8 f16 = 16 B)
    const int gA0   = (wave >> 1) * 4;  // frag: A group base (wm/16)
    const int gB0   = (wave & 1) * 4;   // frag: B group base (wn/16)

    const int npass = (CAUSAL == 2) ? 2 : 1;
    for (int pass = 0; pass < npass; ++pass) {
        const int mt = (CAUSAL == 2 && pass == 1) ? (M / BM - 1 - mtile) : mtile;
        const int m0 = mt * BM;
        const int Kend = (CAUSAL == 2) ? (m0 + BM) : K;

        f32x4 acc[4][4] = {};

        for (int k0 = 0; k0 < Kend; k0 += BK) {
            // stage: wave w covers 16-row groups {2w, 2w+1} of A and B
            #pragma unroll
            for (int gg = 0; gg < 2; ++gg) {
                const int g = wave * 2 + gg;
                gload_lds16(A + (long long)(m0 + g * 16 + srowA) * K + k0 + kq,
                            &As[g * 512]);
                gload_lds16(B + (long long)(n0 + g * 16 + srowA) * K + k0 + kq,
                            &Bs[g * 512]);
            }
            __syncthreads();

            f16x8 af[4], bf[4];
            #pragma unroll
            for (int i = 0; i < 4; ++i)
                af[i] = *(const f16x8*)&As[(gA0 + i) * 512 + lane * 8];
            #pragma unroll
            for (int j = 0; j < 4; ++j)
                bf[j] = *(const f16x8*)&Bs[(gB0 + j) * 512 + lane * 8];
            #pragma unroll
            for (int i = 0; i < 4; ++i)
                #pragma unroll
                for (int j = 0; j < 4; ++j)
                    acc[i][j] = __builtin_amdgcn_mfma_f32_16x16x32_f16(af[i], bf[j], acc[i][j], 0, 0, 0);
            __syncthreads();
        }

        // Epilogue. C/D layout: col = lane&15, row = (lane>>4)*4 + reg  [m89/m91]
        const int wm = (wave >> 1) * 64;
        const int wn = (wave & 1) * 64;
        const int cn = lane & 15;
        const int cm = (lane >> 4) * 4;
        #pragma unroll
        for (int j = 0; j < 4; ++j) {
            const int gn = n0 + wn + j * 16 + cn;
            #pragma unroll
            for (int i = 0; i < 4; ++i) {
                const int gm = m0 + wm + i * 16 + cm;
                if (OUT_MODE == 0) {
                    const float bv = bias ? bias[gn] : 0.f;
                    float* C = (float*)Cv + bz * sCb;
                    #pragma unroll
                    for (int r = 0; r < 4; ++r)
                        C[(long long)(gm + r) * N + gn] = acc[i][j][r] * scale + bv;
                } else if (OUT_MODE == 1) {
                    const float bv = bias ? bias[gn] : 0.f;
                    f16* C = (f16*)Cv + bz * sCb;
                    #pragma unroll
                    for (int r = 0; r < 4; ++r)
                        C[(long long)(gm + r) * N + gn] = (f16)(acc[i][j][r] * scale + bv);
                } else {  // OUT_MODE == 3, fused QKV epilogue
                    const int sel = gn >> 10;
                    const int nn  = gn & 1023;
                    const float* bp = (sel == 0) ? bias : (sel == 1) ? bias2 : bias3;
                    const float bv = bp[nn];
                    if (sel < 2) {
                        f16* C = (f16*)((sel == 0) ? Cv : C2);
                        #pragma unroll
                        for (int r = 0; r < 4; ++r)
                            C[(long long)(gm + r) * 1024 + nn] = (f16)(acc[i][j][r] + bv);
                    } else {
                        f16* C = (f16*)C3;
                        const int b = gm >> 11, s = gm & 2047;
                        f16x4 pk;
                        #pragma unroll
                        for (int r = 0; r < 4; ++r)
                            pk[r] = (f16)(acc[i][j][r] + bv);
                        *(f16x4*)&C[(long long)b * 2097152 + (long long)nn * 2048 + s] = pk;
                    }
                }
            }
        }
        if (CAUSAL == 2) __syncthreads();  // LDS reuse across passes
    }
}

__global__ __launch_bounds__(256)
void cast_to_f16(const float* __restrict__ in, f16* __restrict__ out, int n)
{
    const int i = (blockIdx.x * 256 + threadIdx.x) * 4;
    if (i < n) {
        const float4 v = *(const float4*)&in[i];
        f16x4 o;
        o[0] = (f16)v.x; o[1] = (f16)v.y; o[2] = (f16)v.z; o[3] = (f16)v.w;
        *(f16x4*)&out[i] = o;
    }
}

// out[n][k] = (f16) in[k][n], in: [rows][cols] fp32
__global__ void transpose_cast(const float* __restrict__ in, f16* __restrict__ out,
                               int rows, int cols)
{
    __shared__ f16 tile[32][33];
    const int bx = blockIdx.x * 32;  // col base (n)
    const int by = blockIdx.y * 32;  // row base (k)
    const int tx = threadIdx.x;      // 0..31
    const int ty = threadIdx.y;      // 0..7
    #pragma unroll
    for (int i = 0; i < 32; i += 8)
        tile[ty + i][tx] = (f16)in[(long long)(by + ty + i) * cols + (bx + tx)];
    __syncthreads();
    #pragma unroll
    for (int i = 0; i < 32; i += 8)
        out[(long long)(bx + ty + i) * rows + (by + tx)] = tile[tx][ty + i];
}

// One block per score row (b,q). S = 2048: 8 f16/thread, one 16B load each.
__global__ __launch_bounds__(256)
void softmax_causal(const f16* __restrict__ Sc, f16* __restrict__ P, int S)
{
    const long long row = blockIdx.x;
    const int q = (int)(row % S);
    const f16* src = Sc + row * S;
    f16* dst = P + row * S;
    const int t = threadIdx.x;
    __shared__ float redm[4], reds[4];

    const f16x8 vv = *(const f16x8*)&src[t * 8];
    float v[8];
    float mx = -3.0e38f;
    #pragma unroll
    for (int i = 0; i < 8; ++i) {
        const int k = t * 8 + i;
        v[i] = (float)vv[i];
        if (k <= q) mx = fmaxf(mx, v[i]);
    }
    #pragma unroll
    for (int o = 32; o > 0; o >>= 1) mx = fmaxf(mx, __shfl_down(mx, o));
    if ((t & 63) == 0) redm[t >> 6] = mx;
    __syncthreads();
    mx = fmaxf(fmaxf(redm[0], redm[1]), fmaxf(redm[2], redm[3]));

    float sum = 0.f;
    #pragma unroll
    for (int i = 0; i < 8; ++i) {
        const int k = t * 8 + i;
        v[i] = (k <= q) ? __expf(v[i] - mx) : 0.f;
        sum += v[i];
    }
    #pragma unroll
    for (int o = 32; o > 0; o >>= 1) sum += __shfl_down(sum, o);
    if ((t & 63) == 0) reds[t >> 6] = sum;
    __syncthreads();
    sum = reds[0] + reds[1] + reds[2] + reds[3];
    const float inv = 1.f / sum;
    f16x8 ov;
    #pragma unroll
    for (int i = 0; i < 8; ++i) ov[i] = (f16)(v[i] * inv);
    *(f16x8*)&dst[t * 8] = ov;
}

extern "C" void kernel_launch(void* const* d_in, const int* in_sizes, int n_in,
                              void* d_out, int out_size, void* d_ws, size_t ws_size,
                              hipStream_t stream)
{
    const float* x  = (const float*)d_in[0];
    const float* Wq = (const float*)d_in[1];
    const float* bq = (const float*)d_in[2];
    const float* Wk = (const float*)d_in[3];
    const float* bk = (const float*)d_in[4];
    const float* Wv = (const float*)d_in[5];
    const float* bv = (const float*)d_in[6];
    const float* Wo = (const float*)d_in[7];
    const float* bo = (const float*)d_in[8];
    float* out = (float*)d_out;

    const int B = 4, S = 2048, D = 1024;
    const long long SD  = (long long)S * D;      // 2,097,152
    const long long SS  = (long long)S * S;      // 4,194,304
    const long long BSD = (long long)B * SD;     // 8,388,608
    const int MS = B * S;                        // 8192 flat rows

    char* p = (char*)d_ws;
    f16*   xb   = (f16*)p;  p += BSD * 2;                 // x f16 [8192,1024]
    f16*   Wcat = (f16*)p;  p += 3LL * D * D * 2;         // [Wq^T;Wk^T;Wv^T] f16 [3072,1024]
    f16*   Wot  = (f16*)p;  p += (long long)D * D * 2;    // Wo^T f16
    f16*   Qb   = (f16*)p;  p += BSD * 2;                 // Q f16 [8192,1024]
    f16*   Kb   = (f16*)p;  p += BSD * 2;                 // K f16 [8192,1024]
    f16*   Vt   = (f16*)p;  p += BSD * 2;                 // V^T f16 [B][1024][2048]
    f16*   Sc   = (f16*)p;  p += (long long)B * SS * 2;   // scores f16 [B][S][S]
    f16*   Pb   = (f16*)p;  p += (long long)B * SS * 2;   // probs f16
    f16*   Ab   = xb;  // attn out aliases xb (x dead after QKV projection)

    // 1) casts
    cast_to_f16<<<dim3((unsigned)(BSD / 4 / 256)), dim3(256), 0, stream>>>(x, xb, (int)BSD);
    dim3 tb(32, 8), tg(D / 32, D / 32);
    transpose_cast<<<tg, tb, 0, stream>>>(Wq, Wcat,             D, D);
    transpose_cast<<<tg, tb, 0, stream>>>(Wk, Wcat + D * D,     D, D);
    transpose_cast<<<tg, tb, 0, stream>>>(Wv, Wcat + 2 * D * D, D, D);
    transpose_cast<<<tg, tb, 0, stream>>>(Wo, Wot,              D, D);

    dim3 blk(256);

    // 2) fused QKV projection: [8192,1024] @ [3072,1024]^T -> Q,K flat; V^T batched
    dim3 gqkv(3 * D / BN, MS / BM, 1);   // 24 x 64 = 1536 blocks, 6/CU co-resident
    gemm_bt<3, 0><<<gqkv, blk, 0, stream>>>(xb, Wcat, bq, bk, bv, Qb, Kb, Vt,
                                            MS, 3 * D, D, 0, 0, 0, 1.f);

    // 3) scores = Q K^T / 8, lower-triangle blocks only (136 per batch), f16 out
    dim3 gsc(136, 1, B);
    gemm_bt<1, 1><<<gsc, blk, 0, stream>>>(Qb, Kb, nullptr, nullptr, nullptr,
                                           Sc, nullptr, nullptr,
                                           S, S, D, SD, SD, SS, 0.125f);

    // 4) causal softmax -> P (f16)
    softmax_causal<<<dim3((unsigned)(B * S)), blk, 0, stream>>>(Sc, Pb, S);

    // 5) attn = P @ V; diagonal-paired m-tiles for uniform work (8 pairs)
    dim3 gpv(D / BN, S / BM / 2, B);     // 8 x 8 x 4 = 256 blocks, 2 m-tiles each
    gemm_bt<1, 2><<<gpv, blk, 0, stream>>>(Pb, Vt, nullptr, nullptr, nullptr,
                                           Ab, nullptr, nullptr,
                                           S, D, S, SS, SD, SD, 1.f);

    // 6) out = attn @ Wo^T + bo, fp32, flat M=8192
    dim3 gop(D / BN, MS / BM, 1);        // 8 x 64 = 512 blocks
    gemm_bt<0, 0><<<gop, blk, 0, stream>>>(Ab, Wot, bo, nullptr, nullptr,
                                           out, nullptr, nullptr,
                                           MS, D, D, 0, 0, 0, 1.f);
}

// Round 5
// 320.107 us; speedup vs baseline: 1.2487x; 1.2487x over previous
//
#include <hip/hip_runtime.h>
#include <stdint.h>

typedef _Float16 f16;
typedef __attribute__((ext_vector_type(8))) _Float16 f16x8;
typedef __attribute__((ext_vector_type(4))) _Float16 f16x4;
typedef __attribute__((ext_vector_type(4))) float f32x4;

#define BM 128
#define BN 128
#define BK 32

typedef __attribute__((address_space(3))) uint32_t lds_u32;
typedef const __attribute__((address_space(1))) uint32_t glb_u32;

__device__ __forceinline__ void gload_lds16(const void* g, void* l) {
    // async global->LDS, 16B per lane; LDS dest = wave-uniform base + lane*16
    __builtin_amdgcn_global_load_lds((glb_u32*)g, (lds_u32*)l, 16, 0, 0);
}

// C[M,N] = A[M,K] * B[N,K]^T  (both f16 row-major), fp32 accumulate.
//
// Staging (R2 pattern + XOR swizzle):
//   lane ell stages row (ell>>2) of its 16-row group; within the row it
//   fetches chunk ((ell&3) ^ x(row)), x(r) = (r>>1)&3.  The 4 lanes of a
//   row fetch a PERMUTATION of the same 64B segment -> global coalescing
//   identical to R2 (R3/R4 lesson: scattering lanes across rows breaks
//   quarter-wave coalescing, 4x VMEM requests, -50% perf).
// Fragment read: lane wants (row fr=lane&15, chunk c=lane>>4); it lives at
//   LDS chunk (c ^ x(fr)).  Per 16-lane phase the 16B slots spread 2-way
//   across banks (2-way = free, m136) instead of 8-way (R2: 6.3e6 confl).
// OUT_MODE: 0 = fp32 flat [M,N] + bias
//           1 = f16 out, per-batch stride sCb, row-major [M,N] + bias
//           3 = fused QKV: gn<1024 -> Q flat f16 [M,1024]; <2048 -> K flat;
//               else V^T f16 [B][1024][2048] (batch from gm>>11)
// CAUSAL: 0 = none; 1 = triangular flat blockIdx.x; 2 = PV (Kend=m0+BM,
//         diagonal-paired m-tiles: y and M/BM-1-y)
template<int OUT_MODE, int CAUSAL>
__global__ __launch_bounds__(256, 2)
void gemm_bt(const f16* __restrict__ A, const f16* __restrict__ B,
             const float* __restrict__ bias, const float* __restrict__ bias2,
             const float* __restrict__ bias3,
             void* __restrict__ Cv, void* __restrict__ C2, void* __restrict__ C3,
             int M, int N, int K,
             long long sAb, long long sBb, long long sCb, float scale)
{
    int mtile, n0;
    if (CAUSAL == 1) {
        int rem = (int)blockIdx.x, mi = 0;
        while (rem > mi) { rem -= mi + 1; ++mi; }   // row mi has mi+1 n-blocks
        mtile = mi;
        n0 = rem * BN;
    } else {
        mtile = blockIdx.y;
        n0 = blockIdx.x * BN;
    }

    const int tid  = threadIdx.x;
    const int wave = tid >> 6;
    const int lane = tid & 63;
    const long long bz = blockIdx.z;
    A += bz * sAb;
    B += bz * sBb;

    __shared__ f16 As[BM * BK];  // [128][32] f16, 64B rows, 8 KB
    __shared__ f16 Bs[BM * BK];

    const int srow  = lane >> 2;                              // staging row in group
    const int scolS = (((lane & 3) ^ ((srow >> 1) & 3))) * 8; // swizzled chunk
    const int fr    = lane & 15;                              // frag row in 16-tile
    const int fkS   = (((lane >> 4) ^ ((fr >> 1) & 3))) * 8;  // swizzled frag chunk

    const int wm = (wave >> 1) * 64;
    const int wn = (wave & 1) * 64;

    const int npass = (CAUSAL == 2) ? 2 : 1;
    for (int pass = 0; pass < npass; ++pass) {
        const int mt = (CAUSAL == 2 && pass == 1) ? (M / BM - 1 - mtile) : mtile;
        const int m0 = mt * BM;
        const int Kend = (CAUSAL == 2) ? (m0 + BM) : K;

        f32x4 acc[4][4] = {};

        for (int k0 = 0; k0 < Kend; k0 += BK) {
            #pragma unroll
            for (int i = 0; i < 2; ++i) {
                const int r = wave * 32 + i * 16;  // wave-uniform 16-row group
                gload_lds16(A + (long long)(m0 + r + srow) * K + (k0 + scolS), &As[r * BK]);
                gload_lds16(B + (long long)(n0 + r + srow) * K + (k0 + scolS), &Bs[r * BK]);
            }
            __syncthreads();

            f16x8 af[4], bf[4];
            #pragma unroll
            for (int i = 0; i < 4; ++i)
                af[i] = *(const f16x8*)&As[(wm + i * 16 + fr) * BK + fkS];
            #pragma unroll
            for (int j = 0; j < 4; ++j)
                bf[j] = *(const f16x8*)&Bs[(wn + j * 16 + fr) * BK + fkS];

            #pragma unroll
            for (int i = 0; i < 4; ++i)
                #pragma unroll
                for (int j = 0; j < 4; ++j)
                    acc[i][j] = __builtin_amdgcn_mfma_f32_16x16x32_f16(af[i], bf[j], acc[i][j], 0, 0, 0);
            __syncthreads();
        }

        // Epilogue. C/D layout: col = lane&15, row = (lane>>4)*4 + reg  [m89/m91]
        const int cn = lane & 15;
        const int cm = (lane >> 4) * 4;
        #pragma unroll
        for (int j = 0; j < 4; ++j) {
            const int gn = n0 + wn + j * 16 + cn;
            #pragma unroll
            for (int i = 0; i < 4; ++i) {
                const int gm = m0 + wm + i * 16 + cm;
                if (OUT_MODE == 0) {
                    const float bv = bias ? bias[gn] : 0.f;
                    float* C = (float*)Cv + bz * sCb;
                    #pragma unroll
                    for (int r = 0; r < 4; ++r)
                        C[(long long)(gm + r) * N + gn] = acc[i][j][r] * scale + bv;
                } else if (OUT_MODE == 1) {
                    const float bv = bias ? bias[gn] : 0.f;
                    f16* C = (f16*)Cv + bz * sCb;
                    #pragma unroll
                    for (int r = 0; r < 4; ++r)
                        C[(long long)(gm + r) * N + gn] = (f16)(acc[i][j][r] * scale + bv);
                } else {  // OUT_MODE == 3, fused QKV epilogue
                    const int sel = gn >> 10;
                    const int nn  = gn & 1023;
                    const float* bp = (sel == 0) ? bias : (sel == 1) ? bias2 : bias3;
                    const float bv = bp[nn];
                    if (sel < 2) {
                        f16* C = (f16*)((sel == 0) ? Cv : C2);
                        #pragma unroll
                        for (int r = 0; r < 4; ++r)
                            C[(long long)(gm + r) * 1024 + nn] = (f16)(acc[i][j][r] + bv);
                    } else {
                        f16* C = (f16*)C3;
                        const int b = gm >> 11, s = gm & 2047;
                        f16x4 pk;
                        #pragma unroll
                        for (int r = 0; r < 4; ++r)
                            pk[r] = (f16)(acc[i][j][r] + bv);
                        *(f16x4*)&C[(long long)b * 2097152 + (long long)nn * 2048 + s] = pk;
                    }
                }
            }
        }
        if (CAUSAL == 2) __syncthreads();  // LDS reuse across passes
    }
}

__global__ __launch_bounds__(256)
void cast_to_f16(const float* __restrict__ in, f16* __restrict__ out, int n)
{
    const int i = (blockIdx.x * 256 + threadIdx.x) * 4;
    if (i < n) {
        const float4 v = *(const float4*)&in[i];
        f16x4 o;
        o[0] = (f16)v.x; o[1] = (f16)v.y; o[2] = (f16)v.z; o[3] = (f16)v.w;
        *(f16x4*)&out[i] = o;
    }
}

// out[n][k] = (f16) in[k][n], in: [rows][cols] fp32
__global__ void transpose_cast(const float* __restrict__ in, f16* __restrict__ out,
                               int rows, int cols)
{
    __shared__ f16 tile[32][33];
    const int bx = blockIdx.x * 32;  // col base (n)
    const int by = blockIdx.y * 32;  // row base (k)
    const int tx = threadIdx.x;      // 0..31
    const int ty = threadIdx.y;      // 0..7
    #pragma unroll
    for (int i = 0; i < 32; i += 8)
        tile[ty + i][tx] = (f16)in[(long long)(by + ty + i) * cols + (bx + tx)];
    __syncthreads();
    #pragma unroll
    for (int i = 0; i < 32; i += 8)
        out[(long long)(bx + ty + i) * rows + (by + tx)] = tile[tx][ty + i];
}

// One block per score row (b,q). S = 2048: 8 f16/thread, one 16B load each.
__global__ __launch_bounds__(256)
void softmax_causal(const f16* __restrict__ Sc, f16* __restrict__ P, int S)
{
    const long long row = blockIdx.x;
    const int q = (int)(row % S);
    const f16* src = Sc + row * S;
    f16* dst = P + row * S;
    const int t = threadIdx.x;
    __shared__ float redm[4], reds[4];

    const f16x8 vv = *(const f16x8*)&src[t * 8];
    float v[8];
    float mx = -3.0e38f;
    #pragma unroll
    for (int i = 0; i < 8; ++i) {
        const int k = t * 8 + i;
        v[i] = (float)vv[i];
        if (k <= q) mx = fmaxf(mx, v[i]);
    }
    #pragma unroll
    for (int o = 32; o > 0; o >>= 1) mx = fmaxf(mx, __shfl_down(mx, o));
    if ((t & 63) == 0) redm[t >> 6] = mx;
    __syncthreads();
    mx = fmaxf(fmaxf(redm[0], redm[1]), fmaxf(redm[2], redm[3]));

    float sum = 0.f;
    #pragma unroll
    for (int i = 0; i < 8; ++i) {
        const int k = t * 8 + i;
        v[i] = (k <= q) ? __expf(v[i] - mx) : 0.f;
        sum += v[i];
    }
    #pragma unroll
    for (int o = 32; o > 0; o >>= 1) sum += __shfl_down(sum, o);
    if ((t & 63) == 0) reds[t >> 6] = sum;
    __syncthreads();
    sum = reds[0] + reds[1] + reds[2] + reds[3];
    const float inv = 1.f / sum;
    f16x8 ov;
    #pragma unroll
    for (int i = 0; i < 8; ++i) ov[i] = (f16)(v[i] * inv);
    *(f16x8*)&dst[t * 8] = ov;
}

extern "C" void kernel_launch(void* const* d_in, const int* in_sizes, int n_in,
                              void* d_out, int out_size, void* d_ws, size_t ws_size,
                              hipStream_t stream)
{
    const float* x  = (const float*)d_in[0];
    const float* Wq = (const float*)d_in[1];
    const float* bq = (const float*)d_in[2];
    const float* Wk = (const float*)d_in[3];
    const float* bk = (const float*)d_in[4];
    const float* Wv = (const float*)d_in[5];
    const float* bv = (const float*)d_in[6];
    const float* Wo = (const float*)d_in[7];
    const float* bo = (const float*)d_in[8];
    float* out = (float*)d_out;

    const int B = 4, S = 2048, D = 1024;
    const long long SD  = (long long)S * D;      // 2,097,152
    const long long SS  = (long long)S * S;      // 4,194,304
    const long long BSD = (long long)B * SD;     // 8,388,608
    const int MS = B * S;                        // 8192 flat rows

    char* p = (char*)d_ws;
    f16*   xb   = (f16*)p;  p += BSD * 2;                 // x f16 [8192,1024]
    f16*   Wcat = (f16*)p;  p += 3LL * D * D * 2;         // [Wq^T;Wk^T;Wv^T] f16 [3072,1024]
    f16*   Wot  = (f16*)p;  p += (long long)D * D * 2;    // Wo^T f16
    f16*   Qb   = (f16*)p;  p += BSD * 2;                 // Q f16 [8192,1024]
    f16*   Kb   = (f16*)p;  p += BSD * 2;                 // K f16 [8192,1024]
    f16*   Vt   = (f16*)p;  p += BSD * 2;                 // V^T f16 [B][1024][2048]
    f16*   Sc   = (f16*)p;  p += (long long)B * SS * 2;   // scores f16 [B][S][S]
    f16*   Pb   = (f16*)p;  p += (long long)B * SS * 2;   // probs f16
    f16*   Ab   = xb;  // attn out aliases xb (x dead after QKV projection)

    // 1) casts
    cast_to_f16<<<dim3((unsigned)(BSD / 4 / 256)), dim3(256), 0, stream>>>(x, xb, (int)BSD);
    dim3 tb(32, 8), tg(D / 32, D / 32);
    transpose_cast<<<tg, tb, 0, stream>>>(Wq, Wcat,             D, D);
    transpose_cast<<<tg, tb, 0, stream>>>(Wk, Wcat + D * D,     D, D);
    transpose_cast<<<tg, tb, 0, stream>>>(Wv, Wcat + 2 * D * D, D, D);
    transpose_cast<<<tg, tb, 0, stream>>>(Wo, Wot,              D, D);

    dim3 blk(256);

    // 2) fused QKV projection: [8192,1024] @ [3072,1024]^T -> Q,K flat; V^T batched
    dim3 gqkv(3 * D / BN, MS / BM, 1);   // 24 x 64 = 1536 blocks, 6/CU co-resident
    gemm_bt<3, 0><<<gqkv, blk, 0, stream>>>(xb, Wcat, bq, bk, bv, Qb, Kb, Vt,
                                            MS, 3 * D, D, 0, 0, 0, 1.f);

    // 3) scores = Q K^T / 8, lower-triangle blocks only (136 per batch), f16 out
    dim3 gsc(136, 1, B);
    gemm_bt<1, 1><<<gsc, blk, 0, stream>>>(Qb, Kb, nullptr, nullptr, nullptr,
                                           Sc, nullptr, nullptr,
                                           S, S, D, SD, SD, SS, 0.125f);

    // 4) causal softmax -> P (f16)
    softmax_causal<<<dim3((unsigned)(B * S)), blk, 0, stream>>>(Sc, Pb, S);

    // 5) attn = P @ V; diagonal-paired m-tiles for uniform work (8 pairs)
    dim3 gpv(D / BN, S / BM / 2, B);     // 8 x 8 x 4 = 256 blocks, 2 m-tiles each
    gemm_bt<1, 2><<<gpv, blk, 0, stream>>>(Pb, Vt, nullptr, nullptr, nullptr,
                                           Ab, nullptr, nullptr,
                                           S, D, S, SS, SD, SD, 1.f);

    // 6) out = attn @ Wo^T + bo, fp32, flat M=8192
    dim3 gop(D / BN, MS / BM, 1);        // 8 x 64 = 512 blocks
    gemm_bt<0, 0><<<gop, blk, 0, stream>>>(Ab, Wot, bo, nullptr, nullptr,
                                           out, nullptr, nullptr,
                                           MS, D, D, 0, 0, 0, 1.f);
}

// Round 6
// 308.113 us; speedup vs baseline: 1.2973x; 1.0389x over previous
//
#include <hip/hip_runtime.h>
#include <stdint.h>

typedef _Float16 f16;
typedef __attribute__((ext_vector_type(8))) _Float16 f16x8;
typedef __attribute__((ext_vector_type(4))) _Float16 f16x4;
typedef __attribute__((ext_vector_type(4))) float f32x4;

#define BK 32

typedef __attribute__((address_space(3))) uint32_t lds_u32;
typedef const __attribute__((address_space(1))) uint32_t glb_u32;

__device__ __forceinline__ void gload_lds16(const void* g, void* l) {
    // async global->LDS, 16B per lane; LDS dest = wave-uniform base + lane*16
    __builtin_amdgcn_global_load_lds((glb_u32*)g, (lds_u32*)l, 16, 0, 0);
}

// C[M,N] = A[M,K] * B[N,K]^T  (both f16 row-major), fp32 accumulate.
// Tile TM x TN (template); 4 waves; wave-tile (TM/2)x(TN/2).
// Staging: XOR-swizzled, coalescing-preserving (R5: conflicts == 0, R3/R4
// lesson: never permute lanes across rows -> 4x VMEM requests).
// OUT_MODE: 0 = fp32 [M,N] + bias (scaled)
//           1 = f16 out, per-batch stride sCb, row-major [M,N] + bias
//           3 = fused QKV (TM=TN=128 only): gn<1024 -> Q flat f16;
//               <2048 -> K flat; else Vo^T f16 [B][1024][2048]
// CAUSAL: 0 = none; 1 = triangular flat blockIdx.x (scores);
//         2 = PV: Kend=m0+TM, diagonal-paired m-tiles (y and M/TM-1-y)
template<int OUT_MODE, int CAUSAL, int TM, int TN>
__global__ __launch_bounds__(256, 2)
void gemm_bt(const f16* __restrict__ A, const f16* __restrict__ B,
             const float* __restrict__ bias, const float* __restrict__ bias2,
             const float* __restrict__ bias3,
             void* __restrict__ Cv, void* __restrict__ C2, void* __restrict__ C3,
             int M, int N, int K,
             long long sAb, long long sBb, long long sCb, float scale)
{
    constexpr int IM = TM / 32;   // i-frags per wave
    constexpr int JN = TN / 32;   // j-frags per wave

    int mtile, n0;
    if (CAUSAL == 1) {
        int rem = (int)blockIdx.x, mi = 0;
        while (rem > mi) { rem -= mi + 1; ++mi; }   // row mi has mi+1 n-blocks
        mtile = mi;
        n0 = rem * TN;
    } else {
        mtile = blockIdx.y;
        n0 = blockIdx.x * TN;
    }

    const int tid  = threadIdx.x;
    const int wave = tid >> 6;
    const int lane = tid & 63;
    const long long bz = blockIdx.z;
    A += bz * sAb;
    B += bz * sBb;

    __shared__ f16 As[TM * BK];
    __shared__ f16 Bs[TN * BK];

    const int srow  = lane >> 2;                              // staging row in group
    const int scolS = (((lane & 3) ^ ((srow >> 1) & 3))) * 8; // swizzled chunk
    const int fr    = lane & 15;                              // frag row in 16-tile
    const int fkS   = (((lane >> 4) ^ ((fr >> 1) & 3))) * 8;  // swizzled frag chunk

    const int wm = (wave >> 1) * (TM / 2);
    const int wn = (wave & 1) * (TN / 2);

    const int npass = (CAUSAL == 2) ? 2 : 1;
    for (int pass = 0; pass < npass; ++pass) {
        const int mt = (CAUSAL == 2 && pass == 1) ? (M / TM - 1 - mtile) : mtile;
        const int m0 = mt * TM;
        const int Kend = (CAUSAL == 2) ? (m0 + TM) : K;

        f32x4 acc[IM][JN] = {};

        for (int k0 = 0; k0 < Kend; k0 += BK) {
            #pragma unroll
            for (int gg = 0; gg < TM / 64; ++gg) {
                const int g = wave * (TM / 64) + gg;   // 16-row group of A
                gload_lds16(A + (long long)(m0 + g * 16 + srow) * K + (k0 + scolS),
                            &As[g * 512]);
            }
            #pragma unroll
            for (int gg = 0; gg < TN / 64; ++gg) {
                const int g = wave * (TN / 64) + gg;   // 16-row group of B
                gload_lds16(B + (long long)(n0 + g * 16 + srow) * K + (k0 + scolS),
                            &Bs[g * 512]);
            }
            __syncthreads();

            f16x8 af[IM], bf[JN];
            #pragma unroll
            for (int i = 0; i < IM; ++i)
                af[i] = *(const f16x8*)&As[(wm + i * 16 + fr) * BK + fkS];
            #pragma unroll
            for (int j = 0; j < JN; ++j)
                bf[j] = *(const f16x8*)&Bs[(wn + j * 16 + fr) * BK + fkS];

            #pragma unroll
            for (int i = 0; i < IM; ++i)
                #pragma unroll
                for (int j = 0; j < JN; ++j)
                    acc[i][j] = __builtin_amdgcn_mfma_f32_16x16x32_f16(af[i], bf[j], acc[i][j], 0, 0, 0);
            __syncthreads();
        }

        // Epilogue. C/D layout: col = lane&15, row = (lane>>4)*4 + reg  [m89/m91]
        const int cn = lane & 15;
        const int cm = (lane >> 4) * 4;
        #pragma unroll
        for (int j = 0; j < JN; ++j) {
            const int gn = n0 + wn + j * 16 + cn;
            #pragma unroll
            for (int i = 0; i < IM; ++i) {
                const int gm = m0 + wm + i * 16 + cm;
                if (OUT_MODE == 0) {
                    const float bv = bias ? bias[gn] : 0.f;
                    float* C = (float*)Cv + bz * sCb;
                    #pragma unroll
                    for (int r = 0; r < 4; ++r)
                        C[(long long)(gm + r) * N + gn] = acc[i][j][r] * scale + bv;
                } else if (OUT_MODE == 1) {
                    const float bv = bias ? bias[gn] : 0.f;
                    f16* C = (f16*)Cv + bz * sCb;
                    #pragma unroll
                    for (int r = 0; r < 4; ++r)
                        C[(long long)(gm + r) * N + gn] = (f16)(acc[i][j][r] * scale + bv);
                } else {  // OUT_MODE == 3, fused QKV epilogue (TM=TN=128)
                    const int sel = gn >> 10;
                    const int nn  = gn & 1023;
                    const float* bp = (sel == 0) ? bias : (sel == 1) ? bias2 : bias3;
                    const float bv = bp[nn];
                    if (sel < 2) {
                        f16* C = (f16*)((sel == 0) ? Cv : C2);
                        #pragma unroll
                        for (int r = 0; r < 4; ++r)
                            C[(long long)(gm + r) * 1024 + nn] = (f16)(acc[i][j][r] + bv);
                    } else {
                        f16* C = (f16*)C3;
                        const int b = gm >> 11, s = gm & 2047;
                        f16x4 pk;
                        #pragma unroll
                        for (int r = 0; r < 4; ++r)
                            pk[r] = (f16)(acc[i][j][r] + bv);
                        *(f16x4*)&C[(long long)b * 2097152 + (long long)nn * 2048 + s] = pk;
                    }
                }
            }
        }
        if (CAUSAL == 2) __syncthreads();  // LDS reuse across passes
    }
}

__global__ __launch_bounds__(256)
void cast_to_f16(const float* __restrict__ in, f16* __restrict__ out, int n)
{
    const int i = (blockIdx.x * 256 + threadIdx.x) * 4;
    if (i < n) {
        const float4 v = *(const float4*)&in[i];
        f16x4 o;
        o[0] = (f16)v.x; o[1] = (f16)v.y; o[2] = (f16)v.z; o[3] = (f16)v.w;
        *(f16x4*)&out[i] = o;
    }
}

// out[n][k] = (f16) in[k][n], in: [rows][cols] fp32
__global__ void transpose_cast(const float* __restrict__ in, f16* __restrict__ out,
                               int rows, int cols)
{
    __shared__ f16 tile[32][33];
    const int bx = blockIdx.x * 32;  // col base (n)
    const int by = blockIdx.y * 32;  // row base (k)
    const int tx = threadIdx.x;      // 0..31
    const int ty = threadIdx.y;      // 0..7
    #pragma unroll
    for (int i = 0; i < 32; i += 8)
        tile[ty + i][tx] = (f16)in[(long long)(by + ty + i) * cols + (bx + tx)];
    __syncthreads();
    #pragma unroll
    for (int i = 0; i < 32; i += 8)
        out[(long long)(bx + ty + i) * rows + (by + tx)] = tile[tx][ty + i];
}

// bvo[e] = sum_k bv[k] * Wo[k][e].  grid(16) x block(256): block covers 64 e,
// wave w covers k in [256w, 256w+256), lane l -> e = e0 + l (coalesced rows).
__global__ __launch_bounds__(256)
void bias_vo(const float* __restrict__ bv, const float* __restrict__ Wo,
             float* __restrict__ bvo)
{
    const int e0 = blockIdx.x * 64;
    const int wave = threadIdx.x >> 6, lane = threadIdx.x & 63;
    float acc = 0.f;
    for (int i = 0; i < 256; ++i) {
        const int k = wave * 256 + i;
        acc += bv[k] * Wo[(long long)k * 1024 + e0 + lane];
    }
    __shared__ float red[4][64];
    red[wave][lane] = acc;
    __syncthreads();
    if (wave == 0)
        bvo[e0 + lane] = red[0][lane] + red[1][lane] + red[2][lane] + red[3][lane];
}

// One block per score row (b,q). S = 2048: 8 f16/thread, one 16B load each.
__global__ __launch_bounds__(256)
void softmax_causal(const f16* __restrict__ Sc, f16* __restrict__ P, int S)
{
    const long long row = blockIdx.x;
    const int q = (int)(row % S);
    const f16* src = Sc + row * S;
    f16* dst = P + row * S;
    const int t = threadIdx.x;
    __shared__ float redm[4], reds[4];

    const f16x8 vv = *(const f16x8*)&src[t * 8];
    float v[8];
    float mx = -3.0e38f;
    #pragma unroll
    for (int i = 0; i < 8; ++i) {
        const int k = t * 8 + i;
        v[i] = (float)vv[i];
        if (k <= q) mx = fmaxf(mx, v[i]);
    }
    #pragma unroll
    for (int o = 32; o > 0; o >>= 1) mx = fmaxf(mx, __shfl_down(mx, o));
    if ((t & 63) == 0) redm[t >> 6] = mx;
    __syncthreads();
    mx = fmaxf(fmaxf(redm[0], redm[1]), fmaxf(redm[2], redm[3]));

    float sum = 0.f;
    #pragma unroll
    for (int i = 0; i < 8; ++i) {
        const int k = t * 8 + i;
        v[i] = (k <= q) ? __expf(v[i] - mx) : 0.f;
        sum += v[i];
    }
    #pragma unroll
    for (int o = 32; o > 0; o >>= 1) sum += __shfl_down(sum, o);
    if ((t & 63) == 0) reds[t >> 6] = sum;
    __syncthreads();
    sum = reds[0] + reds[1] + reds[2] + reds[3];
    const float inv = 1.f / sum;
    f16x8 ov;
    #pragma unroll
    for (int i = 0; i < 8; ++i) ov[i] = (f16)(v[i] * inv);
    *(f16x8*)&dst[t * 8] = ov;
}

extern "C" void kernel_launch(void* const* d_in, const int* in_sizes, int n_in,
                              void* d_out, int out_size, void* d_ws, size_t ws_size,
                              hipStream_t stream)
{
    const float* x  = (const float*)d_in[0];
    const float* Wq = (const float*)d_in[1];
    const float* bq = (const float*)d_in[2];
    const float* Wk = (const float*)d_in[3];
    const float* bk = (const float*)d_in[4];
    const float* Wv = (const float*)d_in[5];
    const float* bv = (const float*)d_in[6];
    const float* Wo = (const float*)d_in[7];
    const float* bo = (const float*)d_in[8];
    float* out = (float*)d_out;

    const int B = 4, S = 2048, D = 1024;
    const long long SD  = (long long)S * D;      // 2,097,152
    const long long SS  = (long long)S * S;      // 4,194,304
    const long long BSD = (long long)B * SD;     // 8,388,608
    const int MS = B * S;                        // 8192 flat rows

    char* p = (char*)d_ws;
    f16*   xb   = (f16*)p;  p += BSD * 2;                 // x f16 [8192,1024]
    f16*   Wcat = (f16*)p;  p += 3LL * D * D * 2;         // [Wq^T; Wk^T; Wvo^T] f16
    f16*   Wot  = (f16*)p;  p += (long long)D * D * 2;    // Wo^T f16
    f16*   Wvf  = (f16*)p;  p += (long long)D * D * 2;    // Wv f16 (plain)
    float* bvo  = (float*)p; p += D * 4;                  // bv @ Wo, fp32
    f16*   Qb   = (f16*)p;  p += BSD * 2;                 // Q f16 [8192,1024]
    f16*   Kb   = (f16*)p;  p += BSD * 2;                 // K f16 [8192,1024]
    f16*   Vt   = (f16*)p;  p += BSD * 2;                 // Vo^T f16 [B][1024][2048]
    f16*   Sc   = (f16*)p;  p += (long long)B * SS * 2;   // scores f16 [B][S][S]
    f16*   Pb   = (f16*)p;  p += (long long)B * SS * 2;   // probs f16

    dim3 blk(256);

    // 1) casts / small precomputes
    cast_to_f16<<<dim3((unsigned)(BSD / 4 / 256)), blk, 0, stream>>>(x, xb, (int)BSD);
    dim3 tb(32, 8), tg(D / 32, D / 32);
    transpose_cast<<<tg, tb, 0, stream>>>(Wq, Wcat,         D, D);
    transpose_cast<<<tg, tb, 0, stream>>>(Wk, Wcat + D * D, D, D);
    transpose_cast<<<tg, tb, 0, stream>>>(Wo, Wot,          D, D);
    cast_to_f16<<<dim3((unsigned)(D * D / 4 / 256)), blk, 0, stream>>>(Wv, Wvf, D * D);
    bias_vo<<<dim3(16), blk, 0, stream>>>(bv, Wo, bvo);

    // 2) Wvo^T = Wo^T @ Wv^T  (f16, 64x64 tiles -> 256 blocks), into Wcat block 2
    dim3 gwvo(D / 64, D / 64, 1);
    gemm_bt<1, 0, 64, 64><<<gwvo, blk, 0, stream>>>(Wot, Wvf, nullptr, nullptr, nullptr,
                                                    Wcat + 2 * D * D, nullptr, nullptr,
                                                    D, D, D, 0, 0, 0, 1.f);

    // 3) fused QKVo projection: x @ [Wq^T; Wk^T; Wvo^T]^T -> Q, K flat; Vo^T batched
    dim3 gqkv(3 * D / 128, MS / 128, 1);   // 24 x 64 = 1536 blocks, 6/CU
    gemm_bt<3, 0, 128, 128><<<gqkv, blk, 0, stream>>>(xb, Wcat, bq, bk, bvo, Qb, Kb, Vt,
                                                      MS, 3 * D, D, 0, 0, 0, 1.f);

    // 4) scores = Q K^T / 8, lower-triangle blocks only (136/batch), f16 out
    dim3 gsc(136, 1, B);
    gemm_bt<1, 1, 128, 128><<<gsc, blk, 0, stream>>>(Qb, Kb, nullptr, nullptr, nullptr,
                                                     Sc, nullptr, nullptr,
                                                     S, S, D, SD, SD, SS, 0.125f);

    // 5) causal softmax -> P (f16)
    softmax_causal<<<dim3((unsigned)(B * S)), blk, 0, stream>>>(Sc, Pb, S);

    // 6) out = P @ Vo + bo  (fp32, final output). TN=64 -> 512 uniform blocks
    dim3 gpv(D / 64, S / 128 / 2, B);      // 16 x 8 x 4 = 512 blocks, paired m-tiles
    gemm_bt<0, 2, 128, 64><<<gpv, blk, 0, stream>>>(Pb, Vt, bo, nullptr, nullptr,
                                                    out, nullptr, nullptr,
                                                    S, D, S, SS, SD, SD, 1.f);
}

// Round 7
// 305.133 us; speedup vs baseline: 1.3100x; 1.0098x over previous
//
#include <hip/hip_runtime.h>
#include <stdint.h>

typedef _Float16 f16;
typedef __attribute__((ext_vector_type(8))) _Float16 f16x8;
typedef __attribute__((ext_vector_type(4))) _Float16 f16x4;
typedef __attribute__((ext_vector_type(4))) float f32x4;

#define BK 32

typedef __attribute__((address_space(3))) uint32_t lds_u32;
typedef const __attribute__((address_space(1))) uint32_t glb_u32;

__device__ __forceinline__ void gload_lds16(const void* g, void* l) {
    // async global->LDS, 16B per lane; LDS dest = wave-uniform base + lane*16
    __builtin_amdgcn_global_load_lds((glb_u32*)g, (lds_u32*)l, 16, 0, 0);
}

// C[M,N] = A[M,K] * B[N,K]^T  (both f16 row-major), fp32 accumulate.
// Tile TM x TN (template); 4 waves; wave-tile (TM/2)x(TN/2).
// Staging: XOR-swizzled, coalescing-preserving (R5: conflicts == 0; R3/R4
// lesson: never permute lanes across rows -> 4x VMEM requests).
// OUT_MODE: 0 = fp32 [M,N] + bias (scaled), bias[gn]
//           1 = f16 out, per-batch stride sCb, bias[bz*N+gn] (per-batch col bias)
//           3 = fused proj (TM=TN=128): gn<1024 -> Qh flat f16 [M,1024] (no
//               bias); else Vo^T f16 [B][1024][2048] + bias2 (batch = gm>>11)
// CAUSAL: 0 = none; 1 = triangular flat blockIdx.x (scores);
//         2 = PV: Kend=m0+TM, diagonal-paired m-tiles (y and M/TM-1-y)
template<int OUT_MODE, int CAUSAL, int TM, int TN>
__global__ __launch_bounds__(256, 2)
void gemm_bt(const f16* __restrict__ A, const f16* __restrict__ B,
             const float* __restrict__ bias, const float* __restrict__ bias2,
             void* __restrict__ Cv, void* __restrict__ C2,
             int M, int N, int K,
             long long sAb, long long sBb, long long sCb, float scale)
{
    constexpr int IM = TM / 32;   // i-frags per wave
    constexpr int JN = TN / 32;   // j-frags per wave

    int mtile, n0;
    if (CAUSAL == 1) {
        int rem = (int)blockIdx.x, mi = 0;
        while (rem > mi) { rem -= mi + 1; ++mi; }   // row mi has mi+1 n-blocks
        mtile = mi;
        n0 = rem * TN;
    } else {
        mtile = blockIdx.y;
        n0 = blockIdx.x * TN;
    }

    const int tid  = threadIdx.x;
    const int wave = tid >> 6;
    const int lane = tid & 63;
    const long long bz = blockIdx.z;
    A += bz * sAb;
    B += bz * sBb;

    __shared__ f16 As[TM * BK];
    __shared__ f16 Bs[TN * BK];

    const int srow  = lane >> 2;                              // staging row in group
    const int scolS = (((lane & 3) ^ ((srow >> 1) & 3))) * 8; // swizzled chunk
    const int fr    = lane & 15;                              // frag row in 16-tile
    const int fkS   = (((lane >> 4) ^ ((fr >> 1) & 3))) * 8;  // swizzled frag chunk

    const int wm = (wave >> 1) * (TM / 2);
    const int wn = (wave & 1) * (TN / 2);

    const int npass = (CAUSAL == 2) ? 2 : 1;
    for (int pass = 0; pass < npass; ++pass) {
        const int mt = (CAUSAL == 2 && pass == 1) ? (M / TM - 1 - mtile) : mtile;
        const int m0 = mt * TM;
        const int Kend = (CAUSAL == 2) ? (m0 + TM) : K;

        f32x4 acc[IM][JN] = {};

        for (int k0 = 0; k0 < Kend; k0 += BK) {
            #pragma unroll
            for (int gg = 0; gg < TM / 64; ++gg) {
                const int g = wave * (TM / 64) + gg;   // 16-row group of A
                gload_lds16(A + (long long)(m0 + g * 16 + srow) * K + (k0 + scolS),
                            &As[g * 512]);
            }
            #pragma unroll
            for (int gg = 0; gg < TN / 64; ++gg) {
                const int g = wave * (TN / 64) + gg;   // 16-row group of B
                gload_lds16(B + (long long)(n0 + g * 16 + srow) * K + (k0 + scolS),
                            &Bs[g * 512]);
            }
            __syncthreads();

            f16x8 af[IM], bf[JN];
            #pragma unroll
            for (int i = 0; i < IM; ++i)
                af[i] = *(const f16x8*)&As[(wm + i * 16 + fr) * BK + fkS];
            #pragma unroll
            for (int j = 0; j < JN; ++j)
                bf[j] = *(const f16x8*)&Bs[(wn + j * 16 + fr) * BK + fkS];

            #pragma unroll
            for (int i = 0; i < IM; ++i)
                #pragma unroll
                for (int j = 0; j < JN; ++j)
                    acc[i][j] = __builtin_amdgcn_mfma_f32_16x16x32_f16(af[i], bf[j], acc[i][j], 0, 0, 0);
            __syncthreads();
        }

        // Epilogue. C/D layout: col = lane&15, row = (lane>>4)*4 + reg  [m89/m91]
        const int cn = lane & 15;
        const int cm = (lane >> 4) * 4;
        #pragma unroll
        for (int j = 0; j < JN; ++j) {
            const int gn = n0 + wn + j * 16 + cn;
            #pragma unroll
            for (int i = 0; i < IM; ++i) {
                const int gm = m0 + wm + i * 16 + cm;
                if (OUT_MODE == 0) {
                    const float bv = bias ? bias[gn] : 0.f;
                    float* C = (float*)Cv + bz * sCb;
                    #pragma unroll
                    for (int r = 0; r < 4; ++r)
                        C[(long long)(gm + r) * N + gn] = acc[i][j][r] * scale + bv;
                } else if (OUT_MODE == 1) {
                    const float bv = bias ? bias[(long long)bz * N + gn] : 0.f;
                    f16* C = (f16*)Cv + bz * sCb;
                    #pragma unroll
                    for (int r = 0; r < 4; ++r)
                        C[(long long)(gm + r) * N + gn] = (f16)(acc[i][j][r] * scale + bv);
                } else {  // OUT_MODE == 3: fused Qh/Vo projection (TM=TN=128)
                    const int sel = gn >> 10;
                    const int nn  = gn & 1023;
                    if (sel == 0) {          // Qh flat f16 [M,1024], no bias
                        f16* C = (f16*)Cv;
                        #pragma unroll
                        for (int r = 0; r < 4; ++r)
                            C[(long long)(gm + r) * 1024 + nn] = (f16)acc[i][j][r];
                    } else {                 // Vo^T f16 [B][1024][2048] + bvo
                        const float bb = bias2[nn];
                        f16* C = (f16*)C2;
                        const int b = gm >> 11, s = gm & 2047;
                        f16x4 pk;
                        #pragma unroll
                        for (int r = 0; r < 4; ++r)
                            pk[r] = (f16)(acc[i][j][r] + bb);
                        *(f16x4*)&C[(long long)b * 2097152 + (long long)nn * 2048 + s] = pk;
                    }
                }
            }
        }
        if (CAUSAL == 2) __syncthreads();  // LDS reuse across passes
    }
}

__global__ __launch_bounds__(256)
void cast_to_f16(const float* __restrict__ in, f16* __restrict__ out, int n)
{
    const int i = (blockIdx.x * 256 + threadIdx.x) * 4;
    if (i < n) {
        const float4 v = *(const float4*)&in[i];
        f16x4 o;
        o[0] = (f16)v.x; o[1] = (f16)v.y; o[2] = (f16)v.z; o[3] = (f16)v.w;
        *(f16x4*)&out[i] = o;
    }
}

// out[n][k] = (f16) in[k][n], in: [rows][cols] fp32
__global__ void transpose_cast(const float* __restrict__ in, f16* __restrict__ out,
                               int rows, int cols)
{
    __shared__ f16 tile[32][33];
    const int bx = blockIdx.x * 32;
    const int by = blockIdx.y * 32;
    const int tx = threadIdx.x;      // 0..31
    const int ty = threadIdx.y;      // 0..7
    #pragma unroll
    for (int i = 0; i < 32; i += 8)
        tile[ty + i][tx] = (f16)in[(long long)(by + ty + i) * cols + (bx + tx)];
    __syncthreads();
    #pragma unroll
    for (int i = 0; i < 32; i += 8)
        out[(long long)(bx + ty + i) * rows + (by + tx)] = tile[tx][ty + i];
}

// bvo[e] = sum_k bv[k] * Wo[k][e].
__global__ __launch_bounds__(256)
void bias_vo(const float* __restrict__ bv, const float* __restrict__ Wo,
             float* __restrict__ bvo)
{
    const int e0 = blockIdx.x * 64;
    const int wave = threadIdx.x >> 6, lane = threadIdx.x & 63;
    float acc = 0.f;
    for (int i = 0; i < 256; ++i) {
        const int k = wave * 256 + i;
        acc += bv[k] * Wo[(long long)k * 1024 + e0 + lane];
    }
    __shared__ float red[4][64];
    red[wave][lane] = acc;
    __syncthreads();
    if (wave == 0)
        bvo[e0 + lane] = red[0][lane] + red[1][lane] + red[2][lane] + red[3][lane];
}

// w[d] = (Wk[d,:] . bq) / 8   (fp32). One wave per row.
__global__ __launch_bounds__(256)
void wk_bq(const float* __restrict__ Wk, const float* __restrict__ bq,
           float* __restrict__ w)
{
    const int row = blockIdx.x * 4 + (threadIdx.x >> 6);
    const int lane = threadIdx.x & 63;
    const float* src = Wk + (long long)row * 1024;
    float a = 0.f;
    #pragma unroll
    for (int t = 0; t < 16; ++t) a += src[lane + 64 * t] * bq[lane + 64 * t];
    #pragma unroll
    for (int o = 32; o > 0; o >>= 1) a += __shfl_down(a, o);
    if (lane == 0) w[row] = a * 0.125f;
}

// c[r] = xb[r,:] . w   (f16 x, fp32 w). One wave per row, r = bz*2048 + k.
__global__ __launch_bounds__(256)
void cvec(const f16* __restrict__ xb, const float* __restrict__ w,
          float* __restrict__ c)
{
    const int row = blockIdx.x * 4 + (threadIdx.x >> 6);
    const int lane = threadIdx.x & 63;
    const f16* src = xb + (long long)row * 1024;
    float a = 0.f;
    #pragma unroll
    for (int t = 0; t < 16; ++t) a += (float)src[lane + 64 * t] * w[lane + 64 * t];
    #pragma unroll
    for (int o = 32; o > 0; o >>= 1) a += __shfl_down(a, o);
    if (lane == 0) c[row] = a;
}

// One block per score row (b,q). S = 2048: 8 f16/thread, one 16B load each.
__global__ __launch_bounds__(256)
void softmax_causal(const f16* __restrict__ Sc, f16* __restrict__ P, int S)
{
    const long long row = blockIdx.x;
    const int q = (int)(row % S);
    const f16* src = Sc + row * S;
    f16* dst = P + row * S;
    const int t = threadIdx.x;
    __shared__ float redm[4], reds[4];

    const f16x8 vv = *(const f16x8*)&src[t * 8];
    float v[8];
    float mx = -3.0e38f;
    #pragma unroll
    for (int i = 0; i < 8; ++i) {
        const int k = t * 8 + i;
        v[i] = (float)vv[i];
        if (k <= q) mx = fmaxf(mx, v[i]);
    }
    #pragma unroll
    for (int o = 32; o > 0; o >>= 1) mx = fmaxf(mx, __shfl_down(mx, o));
    if ((t & 63) == 0) redm[t >> 6] = mx;
    __syncthreads();
    mx = fmaxf(fmaxf(redm[0], redm[1]), fmaxf(redm[2], redm[3]));

    float sum = 0.f;
    #pragma unroll
    for (int i = 0; i < 8; ++i) {
        const int k = t * 8 + i;
        v[i] = (k <= q) ? __expf(v[i] - mx) : 0.f;
        sum += v[i];
    }
    #pragma unroll
    for (int o = 32; o > 0; o >>= 1) sum += __shfl_down(sum, o);
    if ((t & 63) == 0) reds[t >> 6] = sum;
    __syncthreads();
    sum = reds[0] + reds[1] + reds[2] + reds[3];
    const float inv = 1.f / sum;
    f16x8 ov;
    #pragma unroll
    for (int i = 0; i < 8; ++i) ov[i] = (f16)(v[i] * inv);
    *(f16x8*)&dst[t * 8] = ov;
}

extern "C" void kernel_launch(void* const* d_in, const int* in_sizes, int n_in,
                              void* d_out, int out_size, void* d_ws, size_t ws_size,
                              hipStream_t stream)
{
    const float* x  = (const float*)d_in[0];
    const float* Wq = (const float*)d_in[1];
    const float* bq = (const float*)d_in[2];
    const float* Wk = (const float*)d_in[3];
    // bk (d_in[4]) is unused: Q.bk^T is row-constant -> softmax-invariant.
    const float* Wv = (const float*)d_in[5];
    const float* bv = (const float*)d_in[6];
    const float* Wo = (const float*)d_in[7];
    const float* bo = (const float*)d_in[8];
    float* out = (float*)d_out;

    const int B = 4, S = 2048, D = 1024;
    const long long SD  = (long long)S * D;      // 2,097,152
    const long long SS  = (long long)S * S;      // 4,194,304
    const long long BSD = (long long)B * SD;     // 8,388,608
    const int MS = B * S;                        // 8192 flat rows

    char* p = (char*)d_ws;
    f16*   xb    = (f16*)p;  p += BSD * 2;                 // x f16 [8192,1024]
    f16*   Wqf   = (f16*)p;  p += (long long)D * D * 2;    // Wq f16 plain
    f16*   Wkf   = (f16*)p;  p += (long long)D * D * 2;    // Wk f16 plain
    f16*   Wvf   = (f16*)p;  p += (long long)D * D * 2;    // Wv f16 plain
    f16*   Wot   = (f16*)p;  p += (long long)D * D * 2;    // Wo^T f16
    f16*   Wcat2 = (f16*)p;  p += 2LL * D * D * 2;         // [WqkT; WvoT] f16 [2048,1024]
    float* bvo   = (float*)p; p += D * 4;                  // bv @ Wo
    float* wv    = (float*)p; p += D * 4;                  // Wk bq / 8
    float* cbias = (float*)p; p += (long long)MS * 4;      // c[r] = x[r].wv
    f16*   Qh    = (f16*)p;  p += BSD * 2;                 // x @ Wqk, f16
    f16*   Vt    = (f16*)p;  p += BSD * 2;                 // Vo^T f16 [B][1024][2048]
    f16*   Sc    = (f16*)p;  p += (long long)B * SS * 2;   // scores f16
    f16*   Pb    = (f16*)p;  p += (long long)B * SS * 2;   // probs f16

    dim3 blk(256);

    // 1) casts / small precomputes
    cast_to_f16<<<dim3((unsigned)(BSD / 4 / 256)), blk, 0, stream>>>(x, xb, (int)BSD);
    cast_to_f16<<<dim3((unsigned)(D * D / 4 / 256)), blk, 0, stream>>>(Wq, Wqf, D * D);
    cast_to_f16<<<dim3((unsigned)(D * D / 4 / 256)), blk, 0, stream>>>(Wk, Wkf, D * D);
    cast_to_f16<<<dim3((unsigned)(D * D / 4 / 256)), blk, 0, stream>>>(Wv, Wvf, D * D);
    dim3 tb(32, 8), tg(D / 32, D / 32);
    transpose_cast<<<tg, tb, 0, stream>>>(Wo, Wot, D, D);
    bias_vo<<<dim3(16), blk, 0, stream>>>(bv, Wo, bvo);
    wk_bq<<<dim3(D / 4), blk, 0, stream>>>(Wk, bq, wv);
    cvec<<<dim3(MS / 4), blk, 0, stream>>>(xb, wv, cbias);

    // 2) weight-product precomputes (both 1024^3 f16 GEMMs, 256 blocks each)
    //    WqkT[e,d] = sum_f Wk[e,f] Wq[d,f]  -> B-rows for Qh = x.Wqk
    //    WvoT[e,d] = sum_k Wo[k,e] Wv[d,k]  -> B-rows for Vo  = x.(WvWo)
    dim3 gw(D / 64, D / 64, 1);
    gemm_bt<1, 0, 64, 64><<<gw, blk, 0, stream>>>(Wkf, Wqf, nullptr, nullptr,
                                                  Wcat2, nullptr,
                                                  D, D, D, 0, 0, 0, 1.f);
    gemm_bt<1, 0, 64, 64><<<gw, blk, 0, stream>>>(Wot, Wvf, nullptr, nullptr,
                                                  Wcat2 + (long long)D * D, nullptr,
                                                  D, D, D, 0, 0, 0, 1.f);

    // 3) fused projection: x @ [WqkT; WvoT]^T -> Qh flat; Vo^T batched (+bvo)
    dim3 gproj(2 * D / 128, MS / 128, 1);   // 16 x 64 = 1024 blocks = 4/CU
    gemm_bt<3, 0, 128, 128><<<gproj, blk, 0, stream>>>(xb, Wcat2, nullptr, bvo,
                                                       Qh, Vt,
                                                       MS, 2 * D, D, 0, 0, 0, 1.f);

    // 4) scores = (Qh x^T)/8 + c[k], lower-triangle blocks only, f16 out
    dim3 gsc(136, 1, B);
    gemm_bt<1, 1, 128, 128><<<gsc, blk, 0, stream>>>(Qh, xb, cbias, nullptr,
                                                     Sc, nullptr,
                                                     S, S, D, SD, SD, SS, 0.125f);

    // 5) causal softmax -> P (f16)
    softmax_causal<<<dim3((unsigned)(B * S)), blk, 0, stream>>>(Sc, Pb, S);

    // 6) out = P @ Vo + bo (fp32 final). TN=64 -> 512 uniform paired blocks
    dim3 gpv(D / 64, S / 128 / 2, B);
    gemm_bt<0, 2, 128, 64><<<gpv, blk, 0, stream>>>(Pb, Vt, bo, nullptr,
                                                    out, nullptr,
                                                    S, D, S, SS, SD, SD, 1.f);
}

// Round 9
// 276.644 us; speedup vs baseline: 1.4449x; 1.1030x over previous
//
#include <hip/hip_runtime.h>
#include <stdint.h>

typedef _Float16 f16;
typedef __attribute__((ext_vector_type(8))) _Float16 f16x8;
typedef __attribute__((ext_vector_type(4))) _Float16 f16x4;
typedef __attribute__((ext_vector_type(4))) float f32x4;

#define BK 32

typedef __attribute__((address_space(3))) uint32_t lds_u32;
typedef const __attribute__((address_space(1))) uint32_t glb_u32;

__device__ __forceinline__ void gload_lds16(const void* g, void* l) {
    // async global->LDS, 16B per lane; LDS dest = wave-uniform base + lane*16
    __builtin_amdgcn_global_load_lds((glb_u32*)g, (lds_u32*)l, 16, 0, 0);
}

// C[M,N] = A[M,K] * B[N,K]^T  (both f16 row-major), fp32 accumulate.
// Tile TM x TN; 4 waves; wave-tile (TM/2)x(TN/2).
// Staging: XOR-swizzled, coalescing-preserving (R5: conflicts == 0; R3/R4
// lesson: never permute lanes across rows -> 4x VMEM requests).
// OUT_MODE: 0 = fp32 [M,N] + bias (scaled), bias[gn]
//           1 = f16 out, per-batch stride sCb, bias[bz*N+gn] (per-batch col bias)
//           3 = fused proj (TM=TN=128): gn<1024 -> Qh flat f16 [M,1024];
//               else Vo^T f16 [B][1024][2048] + bias2 (batch = gm>>11)
// CAUSAL: 0 = none; 1 = triangular flat bx (scores);
//         2 = PV: Kend=m0+TM, diagonal-paired m-tiles (y and M/TM-1-y)
template<int OUT_MODE, int CAUSAL, int TM, int TN>
__device__ __forceinline__
void gemm_body(const f16* __restrict__ A, const f16* __restrict__ B,
               const float* __restrict__ bias, const float* __restrict__ bias2,
               void* __restrict__ Cv, void* __restrict__ C2,
               int M, int N, int K,
               long long sAb, long long sBb, long long sCb, float scale,
               int bx, int by, int bzi)
{
    constexpr int IM = TM / 32;
    constexpr int JN = TN / 32;

    int mtile, n0;
    if (CAUSAL == 1) {
        int rem = bx, mi = 0;
        while (rem > mi) { rem -= mi + 1; ++mi; }   // row mi has mi+1 n-blocks
        mtile = mi;
        n0 = rem * TN;
    } else {
        mtile = by;
        n0 = bx * TN;
    }

    const int tid  = threadIdx.x;
    const int wave = tid >> 6;
    const int lane = tid & 63;
    const long long bz = bzi;
    A += bz * sAb;
    B += bz * sBb;

    __shared__ f16 As[TM * BK];
    __shared__ f16 Bs[TN * BK];

    const int srow  = lane >> 2;                              // staging row in group
    const int scolS = (((lane & 3) ^ ((srow >> 1) & 3))) * 8; // swizzled chunk
    const int fr    = lane & 15;                              // frag row in 16-tile
    const int fkS   = (((lane >> 4) ^ ((fr >> 1) & 3))) * 8;  // swizzled frag chunk

    const int wm = (wave >> 1) * (TM / 2);
    const int wn = (wave & 1) * (TN / 2);

    const int npass = (CAUSAL == 2) ? 2 : 1;
    for (int pass = 0; pass < npass; ++pass) {
        const int mt = (CAUSAL == 2 && pass == 1) ? (M / TM - 1 - mtile) : mtile;
        const int m0 = mt * TM;
        const int Kend = (CAUSAL == 2) ? (m0 + TM) : K;

        f32x4 acc[IM][JN] = {};

        for (int k0 = 0; k0 < Kend; k0 += BK) {
            #pragma unroll
            for (int gg = 0; gg < TM / 64; ++gg) {
                const int g = wave * (TM / 64) + gg;
                gload_lds16(A + (long long)(m0 + g * 16 + srow) * K + (k0 + scolS),
                            &As[g * 512]);
            }
            #pragma unroll
            for (int gg = 0; gg < TN / 64; ++gg) {
                const int g = wave * (TN / 64) + gg;
                gload_lds16(B + (long long)(n0 + g * 16 + srow) * K + (k0 + scolS),
                            &Bs[g * 512]);
            }
            __syncthreads();

            f16x8 af[IM], bf[JN];
            #pragma unroll
            for (int i = 0; i < IM; ++i)
                af[i] = *(const f16x8*)&As[(wm + i * 16 + fr) * BK + fkS];
            #pragma unroll
            for (int j = 0; j < JN; ++j)
                bf[j] = *(const f16x8*)&Bs[(wn + j * 16 + fr) * BK + fkS];

            #pragma unroll
            for (int i = 0; i < IM; ++i)
                #pragma unroll
                for (int j = 0; j < JN; ++j)
                    acc[i][j] = __builtin_amdgcn_mfma_f32_16x16x32_f16(af[i], bf[j], acc[i][j], 0, 0, 0);
            __syncthreads();
        }

        // Epilogue. C/D layout: col = lane&15, row = (lane>>4)*4 + reg  [m89/m91]
        const int cn = lane & 15;
        const int cm = (lane >> 4) * 4;
        #pragma unroll
        for (int j = 0; j < JN; ++j) {
            const int gn = n0 + wn + j * 16 + cn;
            #pragma unroll
            for (int i = 0; i < IM; ++i) {
                const int gm = m0 + wm + i * 16 + cm;
                if (OUT_MODE == 0) {
                    const float bv = bias ? bias[gn] : 0.f;
                    float* C = (float*)Cv + bz * sCb;
                    #pragma unroll
                    for (int r = 0; r < 4; ++r)
                        C[(long long)(gm + r) * N + gn] = acc[i][j][r] * scale + bv;
                } else if (OUT_MODE == 1) {
                    const float bv = bias ? bias[(long long)bz * N + gn] : 0.f;
                    f16* C = (f16*)Cv + bz * sCb;
                    #pragma unroll
                    for (int r = 0; r < 4; ++r)
                        C[(long long)(gm + r) * N + gn] = (f16)(acc[i][j][r] * scale + bv);
                } else {  // OUT_MODE == 3: fused Qh/Vo projection (TM=TN=128)
                    const int sel = gn >> 10;
                    const int nn  = gn & 1023;
                    if (sel == 0) {          // Qh flat f16 [M,1024]
                        f16* C = (f16*)Cv;
                        #pragma unroll
                        for (int r = 0; r < 4; ++r)
                            C[(long long)(gm + r) * 1024 + nn] = (f16)acc[i][j][r];
                    } else {                 // Vo^T f16 [B][1024][2048] + bvo
                        const float bb = bias2[nn];
                        f16* C = (f16*)C2;
                        const int b = gm >> 11, s = gm & 2047;
                        f16x4 pk;
                        #pragma unroll
                        for (int r = 0; r < 4; ++r)
                            pk[r] = (f16)(acc[i][j][r] + bb);
                        *(f16x4*)&C[(long long)b * 2097152 + (long long)nn * 2048 + s] = pk;
                    }
                }
            }
        }
        if (CAUSAL == 2) __syncthreads();  // LDS reuse across passes
    }
}

template<int OUT_MODE, int CAUSAL, int TM, int TN>
__global__ __launch_bounds__(256, 2)
void gemm_bt(const f16* __restrict__ A, const f16* __restrict__ B,
             const float* __restrict__ bias, const float* __restrict__ bias2,
             void* __restrict__ Cv, void* __restrict__ C2,
             int M, int N, int K,
             long long sAb, long long sBb, long long sCb, float scale)
{
    gemm_body<OUT_MODE, CAUSAL, TM, TN>(A, B, bias, bias2, Cv, C2, M, N, K,
                                        sAb, sBb, sCb, scale,
                                        blockIdx.x, blockIdx.y, blockIdx.z);
}

// ---- prep: all input-only transforms in ONE launch ----
// regions (flat blockIdx.x): [0,8192) x-cast; [+1024) Wq cast; [+1024) Wk cast;
// [+1024) Wv cast; [+1024) Wo transpose; [+16) bvo; [+256) wv = Wk.bq/8
__global__ __launch_bounds__(256)
void prep(const float* __restrict__ x,  const float* __restrict__ Wq,
          const float* __restrict__ bq, const float* __restrict__ Wk,
          const float* __restrict__ Wv, const float* __restrict__ bv,
          const float* __restrict__ Wo,
          f16* __restrict__ xb,  f16* __restrict__ Wqf, f16* __restrict__ Wkf,
          f16* __restrict__ Wvf, f16* __restrict__ Wot,
          float* __restrict__ bvo, float* __restrict__ wvec)
{
    __shared__ f16 tile[32][33];
    __shared__ float red[4][64];
    const int t = threadIdx.x;
    int id = blockIdx.x;

    if (id < 8192) {                       // cast x -> xb (f16)
        const int i = (id * 256 + t) * 4;
        const float4 v = *(const float4*)&x[i];
        f16x4 o; o[0]=(f16)v.x; o[1]=(f16)v.y; o[2]=(f16)v.z; o[3]=(f16)v.w;
        *(f16x4*)&xb[i] = o;
        return;
    }
    id -= 8192;
    if (id < 3072) {                       // cast Wq/Wk/Wv (f16)
        const float* src = (id < 1024) ? Wq : (id < 2048) ? Wk : Wv;
        f16* dst = (id < 1024) ? Wqf : (id < 2048) ? Wkf : Wvf;
        const int i = ((id & 1023) * 256 + t) * 4;
        const float4 v = *(const float4*)&src[i];
        f16x4 o; o[0]=(f16)v.x; o[1]=(f16)v.y; o[2]=(f16)v.z; o[3]=(f16)v.w;
        *(f16x4*)&dst[i] = o;
        return;
    }
    id -= 3072;
    if (id < 1024) {                       // Wot[e][k] = (f16) Wo[k][e]
        const int bx = (id & 31) * 32, by = (id >> 5) * 32;
        const int tx = t & 31, ty = t >> 5;
        #pragma unroll
        for (int i = 0; i < 32; i += 8)
            tile[ty + i][tx] = (f16)Wo[(long long)(by + ty + i) * 1024 + (bx + tx)];
        __syncthreads();
        #pragma unroll
        for (int i = 0; i < 32; i += 8)
            Wot[(long long)(bx + ty + i) * 1024 + (by + tx)] = tile[tx][ty + i];
        return;
    }
    id -= 1024;
    if (id < 16) {                         // bvo[e] = sum_k bv[k] Wo[k][e]
        const int e0 = id * 64;
        const int wave = t >> 6, lane = t & 63;
        float acc = 0.f;
        for (int i = 0; i < 256; ++i) {
            const int k = wave * 256 + i;
            acc += bv[k] * Wo[(long long)k * 1024 + e0 + lane];
        }
        red[wave][lane] = acc;
        __syncthreads();
        if (wave == 0)
            bvo[e0 + lane] = red[0][lane] + red[1][lane] + red[2][lane] + red[3][lane];
        return;
    }
    id -= 16;
    {                                      // wvec[d] = (Wk[d,:].bq)/8
        const int row = id * 4 + (t >> 6);
        const int lane = t & 63;
        const float* src = Wk + (long long)row * 1024;
        float a = 0.f;
        #pragma unroll
        for (int tt = 0; tt < 16; ++tt) a += src[lane + 64 * tt] * bq[lane + 64 * tt];
        #pragma unroll
        for (int o = 32; o > 0; o >>= 1) a += __shfl_down(a, o);
        if (lane == 0) wvec[row] = a * 0.125f;
    }
}

// ---- dual: both weight-product GEMMs + cvec in ONE launch ----
// grid (16,16,3): z=0 -> WqkT = Wkf.Wqf^T; z=1 -> WvoT = Wot.Wvf^T;
// z=2 -> cbias[r] = xb[r,:].wvec.  z=2 coverage: 256 blocks x 4 waves x
// 8 rows = ALL 8192 rows (R8 BUG: x2 rows covered only batch 0 -> poisoned
// cbias for batches 1-3, absmax 5.5e-2).
__global__ __launch_bounds__(256, 2)
void dual_weights_cvec(const f16* __restrict__ Wkf, const f16* __restrict__ Wqf,
                       const f16* __restrict__ Wot, const f16* __restrict__ Wvf,
                       f16* __restrict__ Wcat2,
                       const f16* __restrict__ xb, const float* __restrict__ wvec,
                       float* __restrict__ cbias)
{
    if (blockIdx.z == 2) {
        const int flat = blockIdx.y * 16 + blockIdx.x;
        const int wave = threadIdx.x >> 6, lane = threadIdx.x & 63;
        #pragma unroll
        for (int rr = 0; rr < 8; ++rr) {
            const int row = (flat * 4 + wave) * 8 + rr;   // covers 0..8191
            const f16* src = xb + (long long)row * 1024;
            float a = 0.f;
            #pragma unroll
            for (int tt = 0; tt < 16; ++tt)
                a += (float)src[lane + 64 * tt] * wvec[lane + 64 * tt];
            #pragma unroll
            for (int o = 32; o > 0; o >>= 1) a += __shfl_down(a, o);
            if (lane == 0) cbias[row] = a;
        }
        return;
    }
    const f16* Ax = (blockIdx.z == 0) ? Wkf : Wot;
    const f16* Bx = (blockIdx.z == 0) ? Wqf : Wvf;
    f16* Cx = Wcat2 + (long long)blockIdx.z * 1024 * 1024;
    gemm_body<1, 0, 64, 64>(Ax, Bx, nullptr, nullptr, Cx, nullptr,
                            1024, 1024, 1024, 0, 0, 0, 1.f,
                            blockIdx.x, blockIdx.y, 0);
}

// One block per score row (b,q). Predicated 16B loads skip masked chunks.
__global__ __launch_bounds__(256)
void softmax_causal(const f16* __restrict__ Sc, f16* __restrict__ P, int S)
{
    const long long row = blockIdx.x;
    const int q = (int)(row % S);
    const f16* src = Sc + row * S;
    f16* dst = P + row * S;
    const int t = threadIdx.x;
    __shared__ float redm[4], reds[4];

    f16x8 vv = {};
    if (t * 8 <= q) vv = *(const f16x8*)&src[t * 8];
    float v[8];
    float mx = -3.0e38f;
    #pragma unroll
    for (int i = 0; i < 8; ++i) {
        const int k = t * 8 + i;
        v[i] = (float)vv[i];
        if (k <= q) mx = fmaxf(mx, v[i]);
    }
    #pragma unroll
    for (int o = 32; o > 0; o >>= 1) mx = fmaxf(mx, __shfl_down(mx, o));
    if ((t & 63) == 0) redm[t >> 6] = mx;
    __syncthreads();
    mx = fmaxf(fmaxf(redm[0], redm[1]), fmaxf(redm[2], redm[3]));

    float sum = 0.f;
    #pragma unroll
    for (int i = 0; i < 8; ++i) {
        const int k = t * 8 + i;
        v[i] = (k <= q) ? __expf(v[i] - mx) : 0.f;
        sum += v[i];
    }
    #pragma unroll
    for (int o = 32; o > 0; o >>= 1) sum += __shfl_down(sum, o);
    if ((t & 63) == 0) reds[t >> 6] = sum;
    __syncthreads();
    sum = reds[0] + reds[1] + reds[2] + reds[3];
    const float inv = 1.f / sum;
    f16x8 ov;
    #pragma unroll
    for (int i = 0; i < 8; ++i) ov[i] = (f16)(v[i] * inv);
    *(f16x8*)&dst[t * 8] = ov;
}

extern "C" void kernel_launch(void* const* d_in, const int* in_sizes, int n_in,
                              void* d_out, int out_size, void* d_ws, size_t ws_size,
                              hipStream_t stream)
{
    const float* x  = (const float*)d_in[0];
    const float* Wq = (const float*)d_in[1];
    const float* bq = (const float*)d_in[2];
    const float* Wk = (const float*)d_in[3];
    // bk (d_in[4]) unused: Q.bk^T is row-constant -> softmax-invariant.
    const float* Wv = (const float*)d_in[5];
    const float* bv = (const float*)d_in[6];
    const float* Wo = (const float*)d_in[7];
    const float* bo = (const float*)d_in[8];
    float* out = (float*)d_out;

    const int B = 4, S = 2048, D = 1024;
    const long long SD  = (long long)S * D;
    const long long SS  = (long long)S * S;
    const long long BSD = (long long)B * SD;
    const int MS = B * S;

    char* p = (char*)d_ws;
    f16*   xb    = (f16*)p;  p += BSD * 2;
    f16*   Wqf   = (f16*)p;  p += (long long)D * D * 2;
    f16*   Wkf   = (f16*)p;  p += (long long)D * D * 2;
    f16*   Wvf   = (f16*)p;  p += (long long)D * D * 2;
    f16*   Wot   = (f16*)p;  p += (long long)D * D * 2;
    f16*   Wcat2 = (f16*)p;  p += 2LL * D * D * 2;        // [WqkT; WvoT]
    float* bvo   = (float*)p; p += D * 4;
    float* wvec  = (float*)p; p += D * 4;
    float* cbias = (float*)p; p += (long long)MS * 4;
    f16*   Qh    = (f16*)p;  p += BSD * 2;
    f16*   Vt    = (f16*)p;  p += BSD * 2;                // Vo^T [B][1024][2048]
    f16*   Sc    = (f16*)p;  p += (long long)B * SS * 2;
    f16*   Pb    = (f16*)p;  p += (long long)B * SS * 2;

    dim3 blk(256);

    // 1) prep: all casts/transposes/small reductions, one launch (12560 blocks)
    prep<<<dim3(12560), blk, 0, stream>>>(x, Wq, bq, Wk, Wv, bv, Wo,
                                          xb, Wqf, Wkf, Wvf, Wot, bvo, wvec);

    // 2) weight-product GEMMs + cvec, one launch
    dual_weights_cvec<<<dim3(16, 16, 3), blk, 0, stream>>>(Wkf, Wqf, Wot, Wvf,
                                                           Wcat2, xb, wvec, cbias);

    // 3) fused projection: x @ [WqkT; WvoT]^T -> Qh flat; Vo^T batched (+bvo)
    dim3 gproj(2 * D / 128, MS / 128, 1);   // 1024 blocks = 4/CU
    gemm_bt<3, 0, 128, 128><<<gproj, blk, 0, stream>>>(xb, Wcat2, nullptr, bvo,
                                                       Qh, Vt,
                                                       MS, 2 * D, D, 0, 0, 0, 1.f);

    // 4) scores = (Qh x^T)/8 + cbias[k], triangular blocks, f16 out
    dim3 gsc(136, 1, B);
    gemm_bt<1, 1, 128, 128><<<gsc, blk, 0, stream>>>(Qh, xb, cbias, nullptr,
                                                     Sc, nullptr,
                                                     S, S, D, SD, SD, SS, 0.125f);

    // 5) causal softmax -> P (f16), predicated loads
    softmax_causal<<<dim3((unsigned)(B * S)), blk, 0, stream>>>(Sc, Pb, S);

    // 6) out = P @ Vo + bo (fp32 final), diagonal-paired, 512 blocks
    dim3 gpv(D / 64, S / 128 / 2, B);
    gemm_bt<0, 2, 128, 64><<<gpv, blk, 0, stream>>>(Pb, Vt, bo, nullptr,
                                                    out, nullptr,
                                                    S, D, S, SS, SD, SD, 1.f);
}